// Round 5
// baseline (38.603 us; speedup 1.0000x reference)
//
#include <hip/hip_runtime.h>

// DirectVG: batched progressive box adjustment.
// boxes [B,N,4] f32, gt [B,M,4] f32 -> all_boxes [B,6,N,4] ++ all_sims [B,6,N,M]
//
// Wave = 16 rows x 4 m-groups, lane -> (r = lane>>2, g = lane&3).
// Lane computes m = 16k+4g+c (c=0..3) for k=0..6 (k=6 only g=0): each quad is
// a float4 stored DIRECTLY coalesced (4 adjacent lanes = 64B). No LDS
// transpose. Argmax reduced over the 4 g-lanes via 2 quad_perm shuffles; all
// 4 lanes then hold the row's box, so boxes-out is a plain per-lane store.

#define BB 64
#define NN 1000
#define MM 100
#define NITER 5

__global__ __launch_bounds__(128, 8) void dvg_kernel(
    const float* __restrict__ boxes, const float* __restrict__ gt,
    float* __restrict__ out) {
  __shared__ float4 lgt[MM];  // 1.6 KB total LDS

  const int tid = threadIdx.x;
  const int wv = tid >> 6;
  const int lane = tid & 63;
  const int r = lane >> 2;  // row within wave's 16
  const int g = lane & 3;   // m-group
  const int b = blockIdx.x >> 5;
  const int n0 = (blockIdx.x & 31) * 32 + wv * 16;
  const int n = n0 + r;
  const bool vrow = n < NN;          // rows 1000..1023 masked
  const int nc = vrow ? n : NN - 1;  // clamp tail loads

  for (int i = tid; i < MM; i += 128)
    lgt[i] = reinterpret_cast<const float4*>(gt)[b * MM + i];
  __syncthreads();

  const float4 bx = reinterpret_cast<const float4*>(boxes)[b * NN + nc];
  float b0 = bx.x, b1 = bx.y, b2 = bx.z, b3 = bx.w;  // replicated across g

  float* __restrict__ outB = out;                            // [B,6,N,4]
  float* __restrict__ outS = out + (size_t)BB * 6 * NN * 4;  // [B,6,N,M]

  for (int it = 0;; ++it) {
    // keep lgt reads (and gt-area recompute) inside the loop: hoisting 28
    // float4 + areas would need ~140 VGPRs and spill at the (128,8) budget
    asm volatile("" ::: "memory");

    float area = (b2 - b0) * (b3 - b1);
    asm("" : "+v"(area));

    float best = -1.0f;
    int bim = 0;
    const size_t obase = (size_t)(b * 6 + it) * NN + n0;
    float* __restrict__ os = outS + obase * MM + (size_t)r * MM;

#pragma unroll
    for (int k = 0; k < 7; ++k) {
      if (k < 6 || g == 0) {  // quad 4k+g valid (m<100)
        float4 d;
#pragma unroll
        for (int c = 0; c < 4; ++c) {
          const int m = 16 * k + 4 * g + c;
          const float4 q = lgt[m];
          float ag = (q.z - q.x) * (q.w - q.y);
          asm("" : "+v"(ag));
          const float w = fmaxf(fminf(b2, q.z) - fmaxf(b0, q.x), 0.0f);
          const float h = fmaxf(fminf(b3, q.w) - fmaxf(b1, q.y), 0.0f);
          float inter = w * h;
          asm("" : "+v"(inter));
          const float uni = (area + ag) - inter;
          const float val = inter * __builtin_amdgcn_rcpf(uni);
          (&d.x)[c] = val;
          const bool t = val > best;  // strict >: first occurrence in-lane
          best = t ? val : best;
          bim = t ? m : bim;
        }
        if (vrow) *reinterpret_cast<float4*>(os + 16 * k + 4 * g) = d;
      }
    }

    // boxes out: lane 4r+g stores component g of row r's box (no shuffle)
    if (vrow) {
      const float comp = g == 0 ? b0 : (g == 1 ? b1 : (g == 2 ? b2 : b3));
      outB[obase * 4 + lane] = comp;
    }
    if (it == NITER) break;

    // argmax across the 4 g-lanes of each row (tie -> smaller global m)
#pragma unroll
    for (int off = 1; off <= 2; off <<= 1) {
      const float ov = __shfl_xor(best, off, 64);
      const int obi = __shfl_xor(bim, off, 64);
      const bool t = (ov > best) || (ov == best && obi < bim);
      best = t ? ov : best;
      bim = t ? obi : bim;
    }

    const float4 gg = lgt[bim];
    const float dcx = (gg.x + gg.z) * 0.5f - (b0 + b2) * 0.5f;
    const float dcy = (gg.y + gg.w) * 0.5f - (b1 + b3) * 0.5f;
    const float dsx = (gg.z - gg.x) - (b2 - b0);
    const float dsy = (gg.w - gg.y) - (b3 - b1);
    float px = 0.45f * dcx;
    asm("" : "+v"(px));
    float py = 0.45f * dcy;
    asm("" : "+v"(py));
    float qx = 0.4f * (dsx - dcx);
    asm("" : "+v"(qx));
    float qy = 0.4f * (dsy - dcy);
    asm("" : "+v"(qy));
    b0 = b0 + px;
    b1 = b1 + py;
    b2 = (b2 + px) + qx;
    b3 = (b3 + py) + qy;
  }
}

extern "C" void kernel_launch(void* const* d_in, const int* in_sizes, int n_in,
                              void* d_out, int out_size, void* d_ws,
                              size_t ws_size, hipStream_t stream) {
  const float* boxes = (const float*)d_in[0];
  const float* gt = (const float*)d_in[1];
  float* out = (float*)d_out;
  // 32 blocks/batch x 2 waves x 16 rows = 1024 rows >= 1000
  dvg_kernel<<<BB * 32, 128, 0, stream>>>(boxes, gt, out);
}